// Round 8
// baseline (202.869 us; speedup 1.0000x reference)
//
#include <hip/hip_runtime.h>
#include <hip/hip_cooperative_groups.h>
#include <stdint.h>

namespace cg = cooperative_groups;

#define DIM   128
#define MN    1024
#define BATCH 2048
#define ALPHA 0.3f
#define SIGMA 16.0f
#define LOG2E 1.44269504088896f

typedef _Float16 half8 __attribute__((ext_vector_type(8)));
typedef _Float16 half4 __attribute__((ext_vector_type(4)));
typedef float    floatx4 __attribute__((ext_vector_type(4)));

// ws layout (bytes):
//   keys u64[2048]        @ 0        (16 KB)
//   S    f32[1024][128]   @ 16384    (512 KB)
//   cnt  f32[1024]        @ 540672   (4 KB)
//   w2   f32[1024]        @ 544768   (4 KB)
//   wh   f16[1024][128]   @ 548864   (256 KB)
//   wl   f16[1024][128]   @ 811008   (256 KB)
//   xh   f16[2048][128]   @ 1073152  (512 KB)  -> reused as Tg in phase D/E
//   xl   f16[2048][128]   @ 1597440  (512 KB)  -> reused as Tc in phase D/E

// ---------------------------------------------------------------------------
// Single cooperative kernel: 256 blocks x 256 threads (co-resident, 1/CU).
// Phases separated by grid.sync() — replaces 4 kernel dispatches + gaps.
//  A: keys=~0, S/cnt=0, w->(wh,wl)+w2, x->(xh,xl)      [f16 hi/lo split]
//  B: BMU via MFMA (16x16x32_f16, 3-product split), atomicMin keys
//  C: scatter S[v]+=x[b], cnt[v]+=1
//  D: separable conv pass 1 (over vx) -> Tg, Tc
//  E: pass 2 (over vy) + finalize: out = w*(1-rowsum) + delta
// ---------------------------------------------------------------------------
__global__ __launch_bounds__(256) void som_mega(
    const float* __restrict__ x, const float* __restrict__ w,
    const int* __restrict__ itp, float* __restrict__ out, char* __restrict__ ws)
{
  unsigned long long* keys = (unsigned long long*)ws;
  float*    S   = (float*)(ws + 16384);
  float*    cnt = (float*)(ws + 540672);
  float*    w2  = (float*)(ws + 544768);
  _Float16* wh  = (_Float16*)(ws + 548864);
  _Float16* wl  = (_Float16*)(ws + 811008);
  _Float16* xh  = (_Float16*)(ws + 1073152);
  _Float16* xl  = (_Float16*)(ws + 1597440);
  float*    Tg  = (float*)(ws + 1073152);   // reuse xh after phase B
  float*    Tc  = (float*)(ws + 1597440);   // reuse xl after phase B

  __shared__ unsigned long long kb[4][128];
  __shared__ float gxt[64], gyt[64];

  cg::grid_group grid = cg::this_grid();
  const int t   = threadIdx.x;
  const int tid = blockIdx.x * 256 + t;

  // ---------------- Phase A: init + f16 hi/lo conversion ----------------
  if (tid < 2048) {                        // w: half-row each + w2
    int row = tid >> 1, half = tid & 1;
    int base = row * DIM + half * 64;
    float s = 0.f;
#pragma unroll
    for (int q = 0; q < 16; ++q) {
      float4 v = *reinterpret_cast<const float4*>(&w[base + q * 4]);
      s += v.x * v.x + v.y * v.y + v.z * v.z + v.w * v.w;
      half4 h, l;
      h[0] = (_Float16)v.x; l[0] = (_Float16)(v.x - (float)h[0]);
      h[1] = (_Float16)v.y; l[1] = (_Float16)(v.y - (float)h[1]);
      h[2] = (_Float16)v.z; l[2] = (_Float16)(v.z - (float)h[2]);
      h[3] = (_Float16)v.w; l[3] = (_Float16)(v.w - (float)h[3]);
      *reinterpret_cast<half4*>(&wh[base + q * 4]) = h;
      *reinterpret_cast<half4*>(&wl[base + q * 4]) = l;
    }
    s += __shfl_xor(s, 1);
    if (!half) w2[row] = s;
  } else if (tid < 10240) {                // x: quarter-row each
    int idx = tid - 2048;
    int row = idx >> 2, part = idx & 3;
    int base = row * DIM + part * 32;
#pragma unroll
    for (int q = 0; q < 8; ++q) {
      float4 v = *reinterpret_cast<const float4*>(&x[base + q * 4]);
      half4 h, l;
      h[0] = (_Float16)v.x; l[0] = (_Float16)(v.x - (float)h[0]);
      h[1] = (_Float16)v.y; l[1] = (_Float16)(v.y - (float)h[1]);
      h[2] = (_Float16)v.z; l[2] = (_Float16)(v.z - (float)h[2]);
      h[3] = (_Float16)v.w; l[3] = (_Float16)(v.w - (float)h[3]);
      *reinterpret_cast<half4*>(&xh[base + q * 4]) = h;
      *reinterpret_cast<half4*>(&xl[base + q * 4]) = l;
    }
  } else if (tid < 12288) {                // keys = ~0ull
    keys[tid - 10240] = ~0ull;
  } else if (tid < 45312) {                // zero S + cnt (33024 float4)
    reinterpret_cast<float4*>(S)[tid - 12288] = make_float4(0.f, 0.f, 0.f, 0.f);
  }

  grid.sync();

  // ---------------- Phase B: BMU (MFMA) ----------------
  {
    const int lane = t & 63;
    const int wv   = t >> 6;
    const int u0   = (blockIdx.x & 15) * 64 + wv * 16;
    const int b0   = (blockIdx.x >> 4) * 128;
    const int r    = lane & 15;
    const int q    = lane >> 4;

    half8 Ah[4], Al[4];
    {
      const _Float16* wrh = wh + (u0 + r) * DIM + q * 8;
      const _Float16* wrl = wl + (u0 + r) * DIM + q * 8;
#pragma unroll
      for (int c = 0; c < 4; ++c) {
        Ah[c] = *reinterpret_cast<const half8*>(wrh + c * 32);
        Al[c] = *reinterpret_cast<const half8*>(wrl + c * 32);
      }
    }
    float w2r[4];
#pragma unroll
    for (int i = 0; i < 4; ++i) w2r[i] = w2[u0 + q * 4 + i];

#pragma unroll 2
    for (int bt = 0; bt < 8; ++bt) {
      const int b = b0 + bt * 16;
      const _Float16* xrh = xh + (b + r) * DIM + q * 8;
      const _Float16* xrl = xl + (b + r) * DIM + q * 8;
      half8 Bh[4], Bl[4];
#pragma unroll
      for (int c = 0; c < 4; ++c) {
        Bh[c] = *reinterpret_cast<const half8*>(xrh + c * 32);
        Bl[c] = *reinterpret_cast<const half8*>(xrl + c * 32);
      }
      floatx4 acc = {0.f, 0.f, 0.f, 0.f};
#pragma unroll
      for (int c = 0; c < 4; ++c) {
        acc = __builtin_amdgcn_mfma_f32_16x16x32_f16(Ah[c], Bh[c], acc, 0, 0, 0);
        acc = __builtin_amdgcn_mfma_f32_16x16x32_f16(Ah[c], Bl[c], acc, 0, 0, 0);
        acc = __builtin_amdgcn_mfma_f32_16x16x32_f16(Al[c], Bh[c], acc, 0, 0, 0);
      }
      unsigned long long kmin = ~0ull;
#pragma unroll
      for (int i = 0; i < 4; ++i) {
        float s = w2r[i] - 2.0f * acc[i];
        unsigned int sb = __float_as_uint(s);
        sb ^= (sb >> 31) ? 0xFFFFFFFFu : 0x80000000u;   // total order
        unsigned long long key =
            ((unsigned long long)sb << 32) | (unsigned int)(u0 + q * 4 + i);
        if (key < kmin) kmin = key;
      }
      unsigned long long o;
      o = __shfl_xor(kmin, 16); if (o < kmin) kmin = o;
      o = __shfl_xor(kmin, 32); if (o < kmin) kmin = o;
      if (lane < 16) kb[wv][bt * 16 + r] = kmin;
    }
    __syncthreads();
    if (t < 128) {
      unsigned long long m = kb[0][t];
      if (kb[1][t] < m) m = kb[1][t];
      if (kb[2][t] < m) m = kb[2][t];
      if (kb[3][t] < m) m = kb[3][t];
      atomicMin(&keys[b0 + t], m);
    }
  }

  grid.sync();

  // ---------------- Phase C: scatter ----------------
  {
    int b  = tid >> 5;                     // 2048 x 32 = 65536 exactly
    int cq = tid & 31;
    unsigned int v = (unsigned int)keys[b];
    float4 xv = *reinterpret_cast<const float4*>(&x[b * DIM + cq * 4]);
    float* Sv = S + v * DIM + cq * 4;
    unsafeAtomicAdd(&Sv[0], xv.x);
    unsafeAtomicAdd(&Sv[1], xv.y);
    unsafeAtomicAdd(&Sv[2], xv.z);
    unsafeAtomicAdd(&Sv[3], xv.w);
    if (cq == 0) unsafeAtomicAdd(&cnt[v], 1.0f);
  }

  // Gaussian tap tables (needed by D and E)
  {
    const float lr_decay = 1.0f - (float)itp[0] * 0.01f;
    const float alpha_op = ALPHA * lr_decay;
    const float sg       = SIGMA * lr_decay;
    const float c2       = -LOG2E / (sg * sg);
    if (t < 63) {
      float dd = (float)(t - 31);
      float g = __builtin_amdgcn_exp2f(c2 * dd * dd);
      gxt[t] = g;
      gyt[t] = alpha_op * g;               // fold alpha into pass 2
    }
  }

  grid.sync();                             // scatter complete; gxt/gyt visible

  // ---------------- Phase D: conv pass 1 (over vx) ----------------
  if (tid < 32768) {
    int q  = tid & 31;                     // channel quad
    int ux = (tid >> 5) & 31;
    int vy = tid >> 10;
    float a0 = 0.f, a1 = 0.f, a2 = 0.f, a3 = 0.f, ac = 0.f;
    const float* Srow = S + (vy * 32) * DIM + q * 4;
    const float* Crow = cnt + vy * 32;
#pragma unroll 4
    for (int vx = 0; vx < 32; ++vx) {
      float g = gxt[ux - vx + 31];
      float4 s4 = *reinterpret_cast<const float4*>(&Srow[vx * DIM]);
      a0 = fmaf(g, s4.x, a0); a1 = fmaf(g, s4.y, a1);
      a2 = fmaf(g, s4.z, a2); a3 = fmaf(g, s4.w, a3);
      if (q == 0) ac = fmaf(g, Crow[vx], ac);
    }
    float4 r4 = make_float4(a0, a1, a2, a3);
    *reinterpret_cast<float4*>(&Tg[(vy * 32 + ux) * DIM + q * 4]) = r4;
    if (q == 0) Tc[vy * 32 + ux] = ac;
  }

  grid.sync();

  // ---------------- Phase E: conv pass 2 (over vy) + finalize ----------------
  if (tid < 32768) {
    int q  = tid & 31;
    int ux = (tid >> 5) & 31;
    int uy = tid >> 10;
    float d0 = 0.f, d1 = 0.f, d2 = 0.f, d3 = 0.f, rs = 0.f;
#pragma unroll 4
    for (int vy = 0; vy < 32; ++vy) {
      float g = gyt[uy - vy + 31];
      float4 t4 = *reinterpret_cast<const float4*>(&Tg[(vy * 32 + ux) * DIM + q * 4]);
      d0 = fmaf(g, t4.x, d0); d1 = fmaf(g, t4.y, d1);
      d2 = fmaf(g, t4.z, d2); d3 = fmaf(g, t4.w, d3);
      rs = fmaf(g, Tc[vy * 32 + ux], rs);
    }
    int p = uy * 32 + ux;
    float4 wv = *reinterpret_cast<const float4*>(&w[p * DIM + q * 4]);
    float om = 1.0f - rs;
    float4 o;
    o.x = wv.x * om + d0;
    o.y = wv.y * om + d1;
    o.z = wv.z * om + d2;
    o.w = wv.w * om + d3;
    *reinterpret_cast<float4*>(&out[p * DIM + q * 4]) = o;
  }
}

extern "C" void kernel_launch(void* const* d_in, const int* in_sizes, int n_in,
                              void* d_out, int out_size, void* d_ws, size_t ws_size,
                              hipStream_t stream) {
  const float* x   = (const float*)d_in[0];   // [2048,128] f32
  const float* w   = (const float*)d_in[1];   // [1024,128] f32
  const int*   itp = (const int*)d_in[3];     // [1] i32 (meshgrid baked in)
  float* out = (float*)d_out;                 // [1024,128] f32
  char*  ws  = (char*)d_ws;

  void* args[] = {(void*)&x, (void*)&w, (void*)&itp, (void*)&out, (void*)&ws};
  hipLaunchCooperativeKernel((void*)som_mega, dim3(256), dim3(256), args, 0, stream);
}

// Round 9
// 102.384 us; speedup vs baseline: 1.9814x; 1.9814x over previous
//
#include <hip/hip_runtime.h>
#include <stdint.h>

#define DIM   128
#define MN    1024
#define BATCH 2048
#define ALPHA 0.3f
#define SIGMA 16.0f
#define LOG2E 1.44269504088896f

typedef _Float16 half8 __attribute__((ext_vector_type(8)));
typedef _Float16 half4 __attribute__((ext_vector_type(4)));
typedef float    floatx4 __attribute__((ext_vector_type(4)));

// ws layout (bytes):
//   S    f32[1024][128]  @ 0        (512 KB)
//   cnt  f32[1024]       @ 524288   (4 KB)     (S+cnt zeroed as one range)
//   w2   f32[1024]       @ 528384   (4 KB)
//   wh   f16[1024][128]  @ 532480   (256 KB)
//   wl   f16[1024][128]  @ 794624   (256 KB)

// ---------------------------------------------------------------------------
// Kernel 1: prep. blocks 0..7: w -> f16 hi/lo split + w2 (hi+lo carries ~22
// mantissa bits => 3-product MFMA dot is fp32-grade). blocks 8..136: zero
// S+cnt (33024 float4 exactly).
// ---------------------------------------------------------------------------
__global__ __launch_bounds__(256) void prep_kernel(
    const float* __restrict__ w, float* __restrict__ w2,
    _Float16* __restrict__ wh, _Float16* __restrict__ wl,
    float4* __restrict__ Sq)
{
  const int t = threadIdx.x;
  const int bid = blockIdx.x;
  if (bid < 8) {                       // w: 2048 threads, half-row each + w2
    int idx = bid * 256 + t;
    int row = idx >> 1, half = idx & 1;
    int base = row * DIM + half * 64;
    float s = 0.f;
#pragma unroll
    for (int q = 0; q < 16; ++q) {
      float4 v = *reinterpret_cast<const float4*>(&w[base + q * 4]);
      s += v.x * v.x + v.y * v.y + v.z * v.z + v.w * v.w;
      half4 h, l;
      h[0] = (_Float16)v.x; l[0] = (_Float16)(v.x - (float)h[0]);
      h[1] = (_Float16)v.y; l[1] = (_Float16)(v.y - (float)h[1]);
      h[2] = (_Float16)v.z; l[2] = (_Float16)(v.z - (float)h[2]);
      h[3] = (_Float16)v.w; l[3] = (_Float16)(v.w - (float)h[3]);
      *reinterpret_cast<half4*>(&wh[base + q * 4]) = h;
      *reinterpret_cast<half4*>(&wl[base + q * 4]) = l;
    }
    s += __shfl_xor(s, 1);
    if (!half) w2[row] = s;
  } else {                             // zero S + cnt: 129 blocks x 256
    int i = (bid - 8) * 256 + t;       // 33024 float4 = 516 KB
    Sq[i] = make_float4(0.f, 0.f, 0.f, 0.f);
  }
}

// ---------------------------------------------------------------------------
// Kernel 2: BMU + scatter (fused). 128 blocks x 512 thr (8 waves).
// Block owns 16 batches; wave wv sweeps units wv*128..wv*128+127 (8 u-tiles).
// B-frag (x, fixed): converted f32->f16 hi/lo IN-REGISTER per lane (each lane
// needs exactly x[b0+(lane&15)][q*8 + c*32 + j] -> 8 float4 loads + cvt).
// A-frag (w) streamed from wh/wl as 16B contiguous loads. 12 MFMA per u-tile
// (3-product hi/lo split, lolo dropped ~2^-22).
// C/D: col(batch)=lane&15, row(unit)=quad*4+reg  [established R5-R7].
// Argmin completes IN-BLOCK: shfl over quads -> kb[wave][16] -> min over
// 8 waves -> fkey[16]. No atomicMin, no keys array, no init dependency.
// Scatter: thread (bl=t>>5, cq=t&31): S[v] += x[b], cnt[v] += 1, v=argmin.
// S zeroing happened in prep (kernel boundary orders it).
// ---------------------------------------------------------------------------
__global__ __launch_bounds__(512) void bmu_scatter_kernel(
    const float* __restrict__ x, const float* __restrict__ w2,
    const _Float16* __restrict__ wh, const _Float16* __restrict__ wl,
    float* __restrict__ S, float* __restrict__ cnt)
{
  __shared__ unsigned long long kb[8][16];
  __shared__ unsigned long long fkey[16];

  const int t    = threadIdx.x;
  const int lane = t & 63;
  const int wv   = t >> 6;
  const int b0   = blockIdx.x * 16;
  const int r    = lane & 15;
  const int q    = lane >> 4;

  // B-frags from x, in-register hi/lo split
  half8 Bh[4], Bl[4];
  {
    const float* xr = x + (b0 + r) * DIM + q * 8;
#pragma unroll
    for (int c = 0; c < 4; ++c) {
      float4 v0 = *reinterpret_cast<const float4*>(xr + c * 32);
      float4 v1 = *reinterpret_cast<const float4*>(xr + c * 32 + 4);
      float xs[8] = {v0.x, v0.y, v0.z, v0.w, v1.x, v1.y, v1.z, v1.w};
#pragma unroll
      for (int j = 0; j < 8; ++j) {
        _Float16 h = (_Float16)xs[j];
        Bh[c][j] = h;
        Bl[c][j] = (_Float16)(xs[j] - (float)h);
      }
    }
  }

  unsigned long long kmin = ~0ull;
#pragma unroll 2
  for (int ut = 0; ut < 8; ++ut) {
    const int u0 = wv * 128 + ut * 16;
    const _Float16* wrh = wh + (u0 + r) * DIM + q * 8;
    const _Float16* wrl = wl + (u0 + r) * DIM + q * 8;
    half8 Ah[4], Al[4];
#pragma unroll
    for (int c = 0; c < 4; ++c) {
      Ah[c] = *reinterpret_cast<const half8*>(wrh + c * 32);
      Al[c] = *reinterpret_cast<const half8*>(wrl + c * 32);
    }
    floatx4 acc = {0.f, 0.f, 0.f, 0.f};
#pragma unroll
    for (int c = 0; c < 4; ++c) {
      acc = __builtin_amdgcn_mfma_f32_16x16x32_f16(Ah[c], Bh[c], acc, 0, 0, 0);
      acc = __builtin_amdgcn_mfma_f32_16x16x32_f16(Ah[c], Bl[c], acc, 0, 0, 0);
      acc = __builtin_amdgcn_mfma_f32_16x16x32_f16(Al[c], Bh[c], acc, 0, 0, 0);
    }
    float4 w2q = *reinterpret_cast<const float4*>(&w2[u0 + q * 4]);
    float w2a[4] = {w2q.x, w2q.y, w2q.z, w2q.w};
#pragma unroll
    for (int i = 0; i < 4; ++i) {
      float s = w2a[i] - 2.0f * acc[i];
      unsigned int sb = __float_as_uint(s);
      sb ^= (sb >> 31) ? 0xFFFFFFFFu : 0x80000000u;   // total order
      unsigned long long key =
          ((unsigned long long)sb << 32) | (unsigned int)(u0 + q * 4 + i);
      if (key < kmin) kmin = key;
    }
  }
  // reduce over quads (units), then across waves
  unsigned long long o;
  o = __shfl_xor(kmin, 16); if (o < kmin) kmin = o;
  o = __shfl_xor(kmin, 32); if (o < kmin) kmin = o;
  if (lane < 16) kb[wv][r] = kmin;
  __syncthreads();
  if (t < 16) {
    unsigned long long m = kb[0][t];
#pragma unroll
    for (int k = 1; k < 8; ++k)
      if (kb[k][t] < m) m = kb[k][t];
    fkey[t] = m;
  }
  __syncthreads();

  // scatter: 512 threads = 16 batches x 32 quads
  {
    int bl = t >> 5, cq = t & 31;
    unsigned int v = (unsigned int)fkey[bl];         // low 32 = argmin unit
    float4 xv = *reinterpret_cast<const float4*>(&x[(b0 + bl) * DIM + cq * 4]);
    float* Sv = S + v * DIM + cq * 4;
    unsafeAtomicAdd(&Sv[0], xv.x);
    unsafeAtomicAdd(&Sv[1], xv.y);
    unsafeAtomicAdd(&Sv[2], xv.z);
    unsafeAtomicAdd(&Sv[3], xv.w);
    if (cq == 0) unsafeAtomicAdd(&cnt[v], 1.0f);
  }
}

// ---------------------------------------------------------------------------
// Kernel 3: separable-Gaussian conv + finalize (fused). 32 blocks x 512 thr.
// lr[u][v] = alpha * gx(ux-vx) * gy(uy-vy) on the 32x32 meshgrid =>
// delta = Gy (x) ( Gx (x) S ), rowsum likewise from cnt.
// out = w*(1-rowsum) + delta. Block q owns channel quad [4q, 4q+4).
// ---------------------------------------------------------------------------
__global__ __launch_bounds__(512) void convfinal_kernel(
    const float* __restrict__ S, const float* __restrict__ cnt,
    const float* __restrict__ w, const int* __restrict__ itp,
    float* __restrict__ out)
{
  __shared__ float gxt[64], gyt[64];
  __shared__ __align__(16) float T4[1024][4];
  __shared__ float Tc[1024];

  const int t = threadIdx.x;
  const int q = blockIdx.x;

  const float lr_decay = 1.0f - (float)itp[0] * 0.01f;
  const float alpha_op = ALPHA * lr_decay;
  const float sg       = SIGMA * lr_decay;
  const float c2       = -LOG2E / (sg * sg);

  if (t < 63) {
    float dd = (float)(t - 31);
    float g = __builtin_amdgcn_exp2f(c2 * dd * dd);
    gxt[t] = g;
    gyt[t] = alpha_op * g;               // fold alpha into pass 2
  }
  __syncthreads();

#pragma unroll
  for (int r = 0; r < 2; ++r) {
    int p  = t + 512 * r;
    int vy = p >> 5, ux = p & 31;
    float a0 = 0.f, a1 = 0.f, a2 = 0.f, a3 = 0.f, ac = 0.f;
    const float* Srow = S + (vy * 32) * DIM + q * 4;
    const float* Crow = cnt + vy * 32;
#pragma unroll 4
    for (int vx = 0; vx < 32; ++vx) {
      float g = gxt[ux - vx + 31];
      float4 s4 = *reinterpret_cast<const float4*>(&Srow[vx * DIM]);
      a0 = fmaf(g, s4.x, a0); a1 = fmaf(g, s4.y, a1);
      a2 = fmaf(g, s4.z, a2); a3 = fmaf(g, s4.w, a3);
      ac = fmaf(g, Crow[vx], ac);
    }
    T4[p][0] = a0; T4[p][1] = a1; T4[p][2] = a2; T4[p][3] = a3;
    Tc[p] = ac;
  }
  __syncthreads();

#pragma unroll
  for (int r = 0; r < 2; ++r) {
    int p  = t + 512 * r;
    int uy = p >> 5, ux = p & 31;
    float d0 = 0.f, d1 = 0.f, d2 = 0.f, d3 = 0.f, rs = 0.f;
#pragma unroll 4
    for (int vy = 0; vy < 32; ++vy) {
      float g = gyt[uy - vy + 31];
      float4 t4 = *reinterpret_cast<const float4*>(&T4[vy * 32 + ux][0]);
      d0 = fmaf(g, t4.x, d0); d1 = fmaf(g, t4.y, d1);
      d2 = fmaf(g, t4.z, d2); d3 = fmaf(g, t4.w, d3);
      rs = fmaf(g, Tc[vy * 32 + ux], rs);
    }
    float4 wv = *reinterpret_cast<const float4*>(&w[p * DIM + q * 4]);
    float om = 1.0f - rs;
    float4 o;
    o.x = wv.x * om + d0;
    o.y = wv.y * om + d1;
    o.z = wv.z * om + d2;
    o.w = wv.w * om + d3;
    *reinterpret_cast<float4*>(&out[p * DIM + q * 4]) = o;
  }
}

extern "C" void kernel_launch(void* const* d_in, const int* in_sizes, int n_in,
                              void* d_out, int out_size, void* d_ws, size_t ws_size,
                              hipStream_t stream) {
  const float* x   = (const float*)d_in[0];   // [2048,128] f32
  const float* w   = (const float*)d_in[1];   // [1024,128] f32
  const int*   itp = (const int*)d_in[3];     // [1] i32 (meshgrid baked in)
  float* out = (float*)d_out;                 // [1024,128] f32

  char* ws = (char*)d_ws;
  float*     S   = (float*)ws;                // 512 KB
  float*     cnt = (float*)(ws + 524288);     //   4 KB
  float*     w2  = (float*)(ws + 528384);     //   4 KB
  _Float16*  wh  = (_Float16*)(ws + 532480);  // 256 KB
  _Float16*  wl  = (_Float16*)(ws + 794624);  // 256 KB

  prep_kernel<<<137, 256, 0, stream>>>(w, w2, wh, wl, (float4*)S);
  bmu_scatter_kernel<<<128, 512, 0, stream>>>(x, w2, wh, wl, S, cnt);
  convfinal_kernel<<<32, 512, 0, stream>>>(S, cnt, w, itp, out);
}